// Round 8
// baseline (725.484 us; speedup 1.0000x reference)
//
#include <hip/hip_runtime.h>

#define NN 50000
#define NE 400000
#define NBATCH 8
#define DD 128
#define SCAN_BLK 1024

typedef unsigned short u16;
typedef __attribute__((ext_vector_type(8))) short bf16x8;
typedef __attribute__((ext_vector_type(8))) unsigned short u16x8;
typedef __attribute__((ext_vector_type(4))) unsigned short u16x4;
typedef __attribute__((ext_vector_type(4))) float f32x4;
typedef __attribute__((ext_vector_type(2))) float f32x2;

__device__ __forceinline__ u16 f2bf(float f) {
  union { float f; unsigned u; } a; a.f = f;
  unsigned r = a.u + 0x7fffu + ((a.u >> 16) & 1u);
  return (u16)(r >> 16);
}

__device__ __forceinline__ void glds16(const void* g, void* l) {
  __builtin_amdgcn_global_load_lds(
      (const __attribute__((address_space(1))) unsigned*)g,
      (__attribute__((address_space(3))) unsigned*)l, 16, 0, 0);
}

// Convert+transpose fp32 weight [K][128] -> bf16 chunked [K/128][128 n][128 k]
__global__ void wconv_kernel(const float* __restrict__ src, u16* __restrict__ dst, int K) {
  int idx = blockIdx.x * 256 + threadIdx.x;
  if (idx >= K * 128) return;
  int k = idx >> 7, n = idx & 127;
  dst[((k >> 7) << 14) + (n << 7) + (k & 127)] = f2bf(src[idx]);
}

// fp32 -> bf16 flat copy
__global__ void xconv_kernel(const float* __restrict__ x, u16* __restrict__ xbf, int total4) {
  int i = blockIdx.x * 256 + threadIdx.x;
  if (i >= total4) return;
  f32x4 v = ((const f32x4*)x)[i];
  u16x4 o; o[0]=f2bf(v[0]); o[1]=f2bf(v[1]); o[2]=f2bf(v[2]); o[3]=f2bf(v[3]);
  ((u16x4*)xbf)[i] = o;
}

// ---------- CSR prep (R2-proven) ----------
__global__ void ehist_kernel(const int* __restrict__ edge_index, const int* __restrict__ batch,
                             int* __restrict__ cnt, unsigned* __restrict__ ecnt) {
  __shared__ unsigned h[NBATCH];
  if (threadIdx.x < NBATCH) h[threadIdx.x] = 0;
  __syncthreads();
  int e = blockIdx.x * 256 + threadIdx.x;
  if (e < NE) {
    int col = edge_index[NE + e];
    atomicAdd(&cnt[col], 1);
    int row = edge_index[e];
    atomicAdd(&h[batch[row]], 1u);
  }
  __syncthreads();
  if (threadIdx.x < NBATCH) atomicAdd(&ecnt[threadIdx.x], h[threadIdx.x]);
}

__global__ void nhist_kernel(const int* __restrict__ batch, unsigned* __restrict__ ncnt) {
  __shared__ unsigned h[NBATCH];
  if (threadIdx.x < NBATCH) h[threadIdx.x] = 0;
  __syncthreads();
  int i = blockIdx.x * 256 + threadIdx.x;
  if (i < NN) atomicAdd(&h[batch[i]], 1u);
  __syncthreads();
  if (threadIdx.x < NBATCH) atomicAdd(&ncnt[threadIdx.x], h[threadIdx.x]);
}

__global__ void scan1_kernel(const int* __restrict__ cnt, int* __restrict__ offs,
                             int* __restrict__ bsum, int n) {
  __shared__ int lds[256];
  int b0 = blockIdx.x * SCAN_BLK;
  int t = threadIdx.x;
  int i0 = b0 + t * 4;
  int v[4]; int s = 0;
#pragma unroll
  for (int k = 0; k < 4; ++k) { int idx = i0 + k; int c = (idx < n) ? cnt[idx] : 0; v[k] = s; s += c; }
  lds[t] = s;
  __syncthreads();
  for (int off = 1; off < 256; off <<= 1) {
    int x = (t >= off) ? lds[t - off] : 0;
    __syncthreads();
    lds[t] += x;
    __syncthreads();
  }
  int texcl = (t > 0) ? lds[t - 1] : 0;
#pragma unroll
  for (int k = 0; k < 4; ++k) { int idx = i0 + k; if (idx < n) offs[idx] = texcl + v[k]; }
  if (t == 255) bsum[blockIdx.x] = lds[255];
}

__global__ void scan2_kernel(int* __restrict__ bsum, int nb) {
  if (threadIdx.x == 0) {
    int s = 0;
    for (int i = 0; i < nb; ++i) { int c = bsum[i]; bsum[i] = s; s += c; }
  }
}

__global__ void scan3_kernel(int* __restrict__ offs, int* __restrict__ cursor,
                             const int* __restrict__ bsum, int n, int total) {
  int i = blockIdx.x * 256 + threadIdx.x;
  if (i < n) {
    int v = offs[i] + bsum[i / SCAN_BLK];
    offs[i] = v;
    cursor[i] = v;
  }
  if (i == 0) offs[n] = total;
}

__global__ void scatter_kernel(const int* __restrict__ edge_index, int* __restrict__ cursor,
                               int* __restrict__ perm) {
  int e = blockIdx.x * 256 + threadIdx.x;
  if (e < NE) {
    int col = edge_index[NE + e];
    int pos = atomicAdd(&cursor[col], 1);
    perm[pos] = e;
  }
}

// ---------- agg gather-sum: ONE WAVE PER NODE, coalesced 512B rows ----------
__global__ __launch_bounds__(256, 8) void agg_kernel(
    const float* __restrict__ edge_out, const int* __restrict__ offs,
    const int* __restrict__ perm, float* __restrict__ agg) {
  int w = (blockIdx.x * 256 + threadIdx.x) >> 6;   // wave id == node id
  int lane = threadIdx.x & 63;
  if (w >= NN) return;
  int j0 = offs[w], j1 = offs[w + 1];
  const f32x2* base = (const f32x2*)edge_out;
  f32x2 s = {0.f, 0.f};
  int j = j0;
  for (; j + 1 < j1; j += 2) {
    int e0 = perm[j], e1 = perm[j + 1];
    f32x2 v0 = base[(size_t)e0 * 64 + lane];
    f32x2 v1 = base[(size_t)e1 * 64 + lane];
    s += v0; s += v1;
  }
  if (j < j1) {
    int e = perm[j];
    s += base[(size_t)e * 64 + lane];
  }
  ((f32x2*)agg)[(size_t)w * 64 + lane] = s;
}

// ---------------- Edge MLP: 64-edge tile, 32KB dbuf (R7 structure frozen) ----------------
// aggAtomic == nullptr -> CSR mode (no scatter atomics, no ecnt here)
__global__ __launch_bounds__(256, 4) void edge_kernel(
    const u16* __restrict__ xbf, const u16* __restrict__ eabf /*may be null*/,
    const float* __restrict__ ea_f32, const u16* __restrict__ ubf,
    const int* __restrict__ edge_index, const int* __restrict__ batch,
    const u16* __restrict__ w1, const u16* __restrict__ w2, const u16* __restrict__ w3,
    const float* __restrict__ b1, const float* __restrict__ b2, const float* __restrict__ b3,
    float* __restrict__ edge_out, float* aggAtomic,
    float* __restrict__ esum, unsigned* __restrict__ ecnt)
{
  __shared__ u16 As[2][64 * 128];       // 32 KB double buffer
  __shared__ float red[NBATCH][128];
  __shared__ int rows_s[64], cols_s[64], ebat_s[64];
  __shared__ unsigned cnt8[NBATCH];

  const int tid  = threadIdx.x;
  const int lane = tid & 63;
  const int wave = tid >> 6;
  const int wc   = wave;
  const int lr   = lane & 15;
  const int lkb  = lane >> 4;
  const int e0   = blockIdx.x * 64;

  if (tid < 64) {
    int r = edge_index[e0 + tid];
    int c = edge_index[NE + e0 + tid];
    rows_s[tid] = r; cols_s[tid] = c;
    ebat_s[tid] = batch[r];
  }
  for (int i = tid; i < NBATCH * 128; i += 256) (&red[0][0])[i] = 0.f;
  if (tid < NBATCH) cnt8[tid] = 0;

  f32x4 acc[4][2];
#pragma unroll
  for (int m = 0; m < 4; ++m)
#pragma unroll
    for (int n = 0; n < 2; ++n) { acc[m][n][0]=0.f; acc[m][n][1]=0.f; acc[m][n][2]=0.f; acc[m][n][3]=0.f; }

  __syncthreads();

  auto stage = [&](int buf, int c) {
    if (c == 2 && eabf == nullptr) {
#pragma unroll
      for (int j = 0; j < 4; ++j) {
        int idx = j * 64 + lane;
        int rr = wave * 16 + (idx >> 4);
        int k  = idx & 15;
        const float* p = ea_f32 + (size_t)(e0 + rr) * DD + k * 8;
        f32x4 a = *(const f32x4*)p;
        f32x4 b = *(const f32x4*)(p + 4);
        u16x8 v;
        v[0]=f2bf(a[0]); v[1]=f2bf(a[1]); v[2]=f2bf(a[2]); v[3]=f2bf(a[3]);
        v[4]=f2bf(b[0]); v[5]=f2bf(b[1]); v[6]=f2bf(b[2]); v[7]=f2bf(b[3]);
        *(u16x8*)&As[buf][rr * 128 + ((k ^ (rr & 7)) << 3)] = v;
      }
      return;
    }
#pragma unroll
    for (int i = 0; i < 4; ++i) {
      int rr = wave * 16 + i * 4 + (lane >> 4);
      const u16* rp;
      if (c == 0)      rp = xbf + (size_t)rows_s[rr] * DD;
      else if (c == 1) rp = xbf + (size_t)cols_s[rr] * DD;
      else if (c == 2) rp = eabf + (size_t)(e0 + rr) * DD;
      else             rp = ubf + (size_t)ebat_s[rr] * DD;
      const u16* src = rp + (((lane & 15) ^ (rr & 7)) << 3);
      u16* dst = &As[buf][(wave * 16 + i * 4) * 128];
      glds16(src, dst);
    }
  };

  auto compute = [&](const u16* AsBuf, const u16* wsrc) {
#pragma unroll
    for (int kk = 0; kk < 4; ++kk) {
      const int k0 = kk * 32 + lkb * 8;
      bf16x8 af[4], bfv[2];
#pragma unroll
      for (int m = 0; m < 4; ++m) {
        int g = m * 16 + lr;
        int slot = kk * 4 + lkb;
        af[m] = *(const bf16x8*)(AsBuf + g * 128 + ((slot ^ (g & 7)) << 3));
      }
#pragma unroll
      for (int n = 0; n < 2; ++n)
        bfv[n] = *(const bf16x8*)(wsrc + ((wc * 32 + n * 16 + lr) << 7) + k0);
#pragma unroll
      for (int m = 0; m < 4; ++m)
#pragma unroll
        for (int n = 0; n < 2; ++n)
          acc[m][n] = __builtin_amdgcn_mfma_f32_16x16x32_bf16(af[m], bfv[n], acc[m][n], 0, 0, 0);
    }
  };

  auto epi_relu = [&](u16* HsBuf, const float* bias) {
#pragma unroll
    for (int n = 0; n < 2; ++n) {
      int colg = wc * 32 + n * 16 + lr;
      float bv = bias[colg];
      int slot = colg >> 3;
#pragma unroll
      for (int m = 0; m < 4; ++m)
#pragma unroll
        for (int r = 0; r < 4; ++r) {
          int rowg = m * 16 + lkb * 4 + r;
          float v = fmaxf(acc[m][n][r] + bv, 0.f);
          HsBuf[rowg * 128 + ((slot ^ (rowg & 7)) << 3) + (colg & 7)] = f2bf(v);
          acc[m][n][r] = 0.f;
        }
    }
  };

  stage(0, 0);
  __syncthreads();
  stage(1, 1); compute(As[0], w1);                __syncthreads();
  stage(0, 2); compute(As[1], w1 + (1 << 14));    __syncthreads();
  stage(1, 3); compute(As[0], w1 + (2 << 14));    __syncthreads();
               compute(As[1], w1 + (3 << 14));
  epi_relu(As[0], b1);
  __syncthreads();
  compute(As[0], w2);
  __syncthreads();
  epi_relu(As[1], b2);
  __syncthreads();
  compute(As[1], w3);

  // epilogue 3: stores (+ optional fallback atomics) + per-graph esum partials
#pragma unroll
  for (int n = 0; n < 2; ++n) {
    int colg = wc * 32 + n * 16 + lr;
    float bias = b3[colg];
#pragma unroll
    for (int m = 0; m < 4; ++m)
#pragma unroll
      for (int r = 0; r < 4; ++r) {
        int rowg = m * 16 + lkb * 4 + r;
        float v = acc[m][n][r] + bias;
        edge_out[(size_t)(e0 + rowg) * DD + colg] = v;
        if (aggAtomic) atomicAdd(&aggAtomic[(size_t)cols_s[rowg] * DD + colg], v);
        atomicAdd(&red[ebat_s[rowg]][colg], v);
      }
  }
  if (aggAtomic && tid < 64) atomicAdd(&cnt8[ebat_s[tid]], 1u);
  __syncthreads();
  for (int i = tid; i < NBATCH * 128; i += 256) atomicAdd(&esum[i], (&red[0][0])[i]);
  if (aggAtomic && tid < NBATCH) atomicAdd(&ecnt[tid], cnt8[tid]);
}

// ---------------- Node MLP: 64-node tile (R7 structure; agg read from aggsrc) ----------------
__global__ __launch_bounds__(256, 4) void node_kernel(
    const u16* __restrict__ xbf, const float* __restrict__ aggsrc,
    float* __restrict__ x_out,
    const u16* __restrict__ ubf, const int* __restrict__ batch,
    const u16* __restrict__ w1, const u16* __restrict__ w2, const u16* __restrict__ w3,
    const float* __restrict__ b1, const float* __restrict__ b2, const float* __restrict__ b3,
    float* __restrict__ nsum)
{
  __shared__ u16 As[2][64 * 128];
  __shared__ float red[NBATCH][128];
  __shared__ int nbat_s[64];

  const int tid  = threadIdx.x;
  const int lane = tid & 63;
  const int wave = tid >> 6;
  const int wc   = wave;
  const int lr   = lane & 15;
  const int lkb  = lane >> 4;
  const int n0   = blockIdx.x * 64;

  if (tid < 64) {
    int node = n0 + tid;
    nbat_s[tid] = (node < NN) ? batch[node] : 0;
  }
  for (int i = tid; i < NBATCH * 128; i += 256) (&red[0][0])[i] = 0.f;

  f32x4 acc[4][2];
#pragma unroll
  for (int m = 0; m < 4; ++m)
#pragma unroll
    for (int n = 0; n < 2; ++n) { acc[m][n][0]=0.f; acc[m][n][1]=0.f; acc[m][n][2]=0.f; acc[m][n][3]=0.f; }

  __syncthreads();

  auto stage_bf = [&](int buf, int c) {
#pragma unroll
    for (int i = 0; i < 4; ++i) {
      int rr = wave * 16 + i * 4 + (lane >> 4);
      int node = n0 + rr; if (node >= NN) node = 0;
      const u16* rp = (c == 0) ? (xbf + (size_t)node * DD)
                               : (ubf + (size_t)nbat_s[rr] * DD);
      const u16* src = rp + (((lane & 15) ^ (rr & 7)) << 3);
      u16* dst = &As[buf][(wave * 16 + i * 4) * 128];
      glds16(src, dst);
    }
  };

  auto stage_agg = [&](int buf) {
#pragma unroll
    for (int j = 0; j < 4; ++j) {
      int idx = j * 64 + lane;
      int rr = wave * 16 + (idx >> 4);
      int k  = idx & 15;
      int node = n0 + rr; if (node >= NN) node = 0;
      const float* p = aggsrc + (size_t)node * DD + k * 8;
      f32x4 a = *(const f32x4*)p;
      f32x4 b = *(const f32x4*)(p + 4);
      u16x8 v;
      v[0]=f2bf(a[0]); v[1]=f2bf(a[1]); v[2]=f2bf(a[2]); v[3]=f2bf(a[3]);
      v[4]=f2bf(b[0]); v[5]=f2bf(b[1]); v[6]=f2bf(b[2]); v[7]=f2bf(b[3]);
      *(u16x8*)&As[buf][rr * 128 + ((k ^ (rr & 7)) << 3)] = v;
    }
  };

  auto compute = [&](const u16* AsBuf, const u16* wsrc) {
#pragma unroll
    for (int kk = 0; kk < 4; ++kk) {
      const int k0 = kk * 32 + lkb * 8;
      bf16x8 af[4], bfv[2];
#pragma unroll
      for (int m = 0; m < 4; ++m) {
        int g = m * 16 + lr;
        int slot = kk * 4 + lkb;
        af[m] = *(const bf16x8*)(AsBuf + g * 128 + ((slot ^ (g & 7)) << 3));
      }
#pragma unroll
      for (int n = 0; n < 2; ++n)
        bfv[n] = *(const bf16x8*)(wsrc + ((wc * 32 + n * 16 + lr) << 7) + k0);
#pragma unroll
      for (int m = 0; m < 4; ++m)
#pragma unroll
        for (int n = 0; n < 2; ++n)
          acc[m][n] = __builtin_amdgcn_mfma_f32_16x16x32_bf16(af[m], bfv[n], acc[m][n], 0, 0, 0);
    }
  };

  auto epi_relu = [&](u16* HsBuf, const float* bias) {
#pragma unroll
    for (int n = 0; n < 2; ++n) {
      int colg = wc * 32 + n * 16 + lr;
      float bv = bias[colg];
      int slot = colg >> 3;
#pragma unroll
      for (int m = 0; m < 4; ++m)
#pragma unroll
        for (int r = 0; r < 4; ++r) {
          int rowg = m * 16 + lkb * 4 + r;
          float v = fmaxf(acc[m][n][r] + bv, 0.f);
          HsBuf[rowg * 128 + ((slot ^ (rowg & 7)) << 3) + (colg & 7)] = f2bf(v);
          acc[m][n][r] = 0.f;
        }
    }
  };

  stage_bf(0, 0);
  __syncthreads();
  stage_agg(1);   compute(As[0], w1);               __syncthreads();
  stage_bf(0, 2); compute(As[1], w1 + (1 << 14));   __syncthreads();
                  compute(As[0], w1 + (2 << 14));
  epi_relu(As[1], b1);
  __syncthreads();
  compute(As[1], w2);
  __syncthreads();
  epi_relu(As[0], b2);
  __syncthreads();
  compute(As[0], w3);

#pragma unroll
  for (int n = 0; n < 2; ++n) {
    int colg = wc * 32 + n * 16 + lr;
    float bias = b3[colg];
#pragma unroll
    for (int m = 0; m < 4; ++m)
#pragma unroll
      for (int r = 0; r < 4; ++r) {
        int rowg = m * 16 + lkb * 4 + r;
        int node = n0 + rowg;
        if (node < NN) {
          float v = acc[m][n][r] + bias;
          x_out[(size_t)node * DD + colg] = v;
          atomicAdd(&red[nbat_s[rowg]][colg], v);
        }
      }
  }
  __syncthreads();
  for (int i = tid; i < NBATCH * 128; i += 256) atomicAdd(&nsum[i], (&red[0][0])[i]);
}

// ---------------- Global MLP (fp32, tiny) ----------------
__global__ void global_kernel(
    const float* __restrict__ u,
    const float* __restrict__ nsum, const unsigned* __restrict__ ncnt,
    const float* __restrict__ esum, const unsigned* __restrict__ ecnt,
    const float* __restrict__ gW1, const float* __restrict__ gb1,
    const float* __restrict__ gW2, const float* __restrict__ gb2,
    const float* __restrict__ gW3, const float* __restrict__ gb3,
    float* __restrict__ u_out)
{
  __shared__ float gin[NBATCH][384];
  __shared__ float h1[NBATCH][128];
  __shared__ float h2[NBATCH][128];
  int tid = threadIdx.x;
  for (int i = tid; i < NBATCH * 128; i += 256) {
    int r = i >> 7, c = i & 127;
    float nc = (float)(ncnt[r] < 1u ? 1u : ncnt[r]);
    float ec = (float)(ecnt[r] < 1u ? 1u : ecnt[r]);
    gin[r][c] = u[i];
    gin[r][128 + c] = nsum[i] / nc;
    gin[r][256 + c] = esum[i] / ec;
  }
  __syncthreads();
  for (int o = tid; o < NBATCH * 128; o += 256) {
    int r = o >> 7, n = o & 127;
    float s = gb1[n];
    for (int k = 0; k < 384; ++k) s += gin[r][k] * gW1[k * 128 + n];
    h1[r][n] = fmaxf(s, 0.f);
  }
  __syncthreads();
  for (int o = tid; o < NBATCH * 128; o += 256) {
    int r = o >> 7, n = o & 127;
    float s = gb2[n];
    for (int k = 0; k < 128; ++k) s += h1[r][k] * gW2[k * 128 + n];
    h2[r][n] = fmaxf(s, 0.f);
  }
  __syncthreads();
  for (int o = tid; o < NBATCH * 128; o += 256) {
    int r = o >> 7, n = o & 127;
    float s = gb3[n];
    for (int k = 0; k < 128; ++k) s += h2[r][k] * gW3[k * 128 + n];
    u_out[o] = s;
  }
}

extern "C" void kernel_launch(void* const* d_in, const int* in_sizes, int n_in,
                              void* d_out, int out_size, void* d_ws, size_t ws_size,
                              hipStream_t stream) {
  const float* x          = (const float*)d_in[0];
  const int*   edge_index = (const int*)d_in[1];
  const float* edge_attr  = (const float*)d_in[2];
  const float* u          = (const float*)d_in[3];
  const int*   batch      = (const int*)d_in[4];
  const float* eW1 = (const float*)d_in[5];  const float* eb1 = (const float*)d_in[6];
  const float* eW2 = (const float*)d_in[7];  const float* eb2 = (const float*)d_in[8];
  const float* eW3 = (const float*)d_in[9];  const float* eb3 = (const float*)d_in[10];
  const float* nW1 = (const float*)d_in[11]; const float* nb1 = (const float*)d_in[12];
  const float* nW2 = (const float*)d_in[13]; const float* nb2 = (const float*)d_in[14];
  const float* nW3 = (const float*)d_in[15]; const float* nb3 = (const float*)d_in[16];
  const float* gW1 = (const float*)d_in[17]; const float* gb1 = (const float*)d_in[18];
  const float* gW2 = (const float*)d_in[19]; const float* gb2 = (const float*)d_in[20];
  const float* gW3 = (const float*)d_in[21]; const float* gb3 = (const float*)d_in[22];

  float* out      = (float*)d_out;
  float* x_out    = out;                                  // [NN][128]
  float* edge_out = out + (size_t)NN * DD;                // [NE][128]
  float* u_out    = out + (size_t)(NN + NE) * DD;         // [8][128]

  char* ws = (char*)d_ws;
  u16* wE1t = (u16*)(ws + 0);         // 131072
  u16* wE2t = (u16*)(ws + 131072);    // 32768
  u16* wE3t = (u16*)(ws + 163840);    // 32768
  u16* wN1t = (u16*)(ws + 196608);    // 98304
  u16* wN2t = (u16*)(ws + 294912);    // 32768
  u16* wN3t = (u16*)(ws + 327680);    // 32768
  float*    esum = (float*)(ws + 360448);     // 4096
  float*    nsum = (float*)(ws + 364544);     // 4096
  unsigned* ecnt = (unsigned*)(ws + 368640);  // 32
  unsigned* ncnt = (unsigned*)(ws + 368672);  // 32
  u16*      ubf  = (u16*)(ws + 369664);       // 2048
  u16*      xbf  = (u16*)(ws + 393216);       // 12,800,000 -> ends 13,193,216
  const size_t EABF_OFF = 13193216;
  const size_t EABF_END = EABF_OFF + (size_t)NE * DD * 2;   // 115,593,216
  u16* eabf = (ws_size >= EABF_END) ? (u16*)(ws + EABF_OFF) : nullptr;

  // CSR region after eabf
  const size_t CNT_OFF    = 115593216;                       // 200,000
  const size_t OFFS_OFF   = 115793216;                       // 200,004
  const size_t CURSOR_OFF = 115993600;                       // 200,000
  const size_t BSUM_OFF   = 116193600;                       // ~200 -> pad
  const size_t PERM_OFF   = 116194304;                       // 1,600,000
  const size_t AGG_OFF    = 117794304;                       // 25,600,000
  const size_t CSR_END    = AGG_OFF + (size_t)NN * DD * 4;   // 143,394,304
  const bool HAVE_CSR = (ws_size >= CSR_END);

  int*   cnt    = (int*)(ws + CNT_OFF);
  int*   offs   = (int*)(ws + OFFS_OFF);
  int*   cursor = (int*)(ws + CURSOR_OFF);
  int*   bsum   = (int*)(ws + BSUM_OFF);
  int*   perm   = (int*)(ws + PERM_OFF);
  float* agg    = (float*)(ws + AGG_OFF);

  // zero stat accumulators every launch
  hipMemsetAsync(ws + 360448, 0, 8288, stream);

  wconv_kernel<<<256, 256, 0, stream>>>(eW1, wE1t, 512);
  wconv_kernel<<<64, 256, 0, stream>>>(eW2, wE2t, 128);
  wconv_kernel<<<64, 256, 0, stream>>>(eW3, wE3t, 128);
  wconv_kernel<<<192, 256, 0, stream>>>(nW1, wN1t, 384);
  wconv_kernel<<<64, 256, 0, stream>>>(nW2, wN2t, 128);
  wconv_kernel<<<64, 256, 0, stream>>>(nW3, wN3t, 128);
  xconv_kernel<<<6250, 256, 0, stream>>>(x, xbf, NN * DD / 4);
  xconv_kernel<<<1, 256, 0, stream>>>(u, ubf, NBATCH * DD / 4);
  if (eabf)
    xconv_kernel<<<50000, 256, 0, stream>>>(edge_attr, eabf, NE * DD / 4);

  nhist_kernel<<<(NN + 255) / 256, 256, 0, stream>>>(batch, ncnt);

  if (HAVE_CSR) {
    // CSR prep (ehist also produces ecnt)
    hipMemsetAsync(ws + CNT_OFF, 0, (size_t)NN * 4, stream);
    ehist_kernel<<<(NE + 255) / 256, 256, 0, stream>>>(edge_index, batch, cnt, ecnt);
    scan1_kernel<<<(NN + SCAN_BLK - 1) / SCAN_BLK, 256, 0, stream>>>(cnt, offs, bsum, NN);
    scan2_kernel<<<1, 64, 0, stream>>>(bsum, (NN + SCAN_BLK - 1) / SCAN_BLK);
    scan3_kernel<<<(NN + 255) / 256, 256, 0, stream>>>(offs, cursor, bsum, NN, NE);
    scatter_kernel<<<(NE + 255) / 256, 256, 0, stream>>>(edge_index, cursor, perm);

    edge_kernel<<<NE / 64, 256, 0, stream>>>(
        xbf, eabf, edge_attr, ubf, edge_index, batch,
        wE1t, wE2t, wE3t, eb1, eb2, eb3,
        edge_out, nullptr /*no scatter atomics*/, esum, ecnt);

    agg_kernel<<<(NN * 64 + 255) / 256, 256, 0, stream>>>(edge_out, offs, perm, agg);

    node_kernel<<<(NN + 63) / 64, 256, 0, stream>>>(
        xbf, agg, x_out, ubf, batch,
        wN1t, wN2t, wN3t, nb1, nb2, nb3, nsum);
  } else {
    // fallback: R7 device-atomic path (agg accumulated in x_out region)
    hipMemsetAsync(d_out, 0, (size_t)NN * DD * sizeof(float), stream);
    edge_kernel<<<NE / 64, 256, 0, stream>>>(
        xbf, eabf, edge_attr, ubf, edge_index, batch,
        wE1t, wE2t, wE3t, eb1, eb2, eb3,
        edge_out, x_out /*atomic agg*/, esum, ecnt);
    node_kernel<<<(NN + 63) / 64, 256, 0, stream>>>(
        xbf, x_out /*agg in*/, x_out /*x_out over same rows*/, ubf, batch,
        wN1t, wN2t, wN3t, nb1, nb2, nb3, nsum);
  }

  global_kernel<<<1, 256, 0, stream>>>(
      u, nsum, ncnt, esum, ecnt,
      gW1, gb1, gW2, gb2, gW3, gb3, u_out);
}